// Round 1
// baseline (585.814 us; speedup 1.0000x reference)
//
#include <hip/hip_runtime.h>
#include <hip/hip_bf16.h>

#define NB 4
#define NS 2048
#define ND 1024
#define NH 16
#define NDH 64

typedef __attribute__((ext_vector_type(8))) __bf16 bf16x8;
typedef __attribute__((ext_vector_type(4))) float f32x4;

__device__ __forceinline__ unsigned short f2bf(float f) {
  union { float f; unsigned u; } v; v.f = f;
  unsigned r = v.u + 0x7FFFu + ((v.u >> 16) & 1u);
  return (unsigned short)(r >> 16);
}

// ---------------------------------------------------------------------------
// QKV projection: Y = X @ W^T + bias  (X fp32 [8192,1024], W fp32 [1024,1024])
// Scatter epilogue to [B,H,S,DH] bf16. Q gets scale = (1/sqrt(DH)) * log2(e)
// folded in so attention can use exp2.
// ---------------------------------------------------------------------------
__global__ __launch_bounds__(256) void gemm_qkv(
    const float* __restrict__ xq, const float* __restrict__ xk, const float* __restrict__ xv,
    const float* __restrict__ wq, const float* __restrict__ wk, const float* __restrict__ wv,
    const float* __restrict__ bq, const float* __restrict__ bk, const float* __restrict__ bv,
    unsigned short* __restrict__ Qh, unsigned short* __restrict__ Kh, unsigned short* __restrict__ Vh)
{
  const int z = blockIdx.z;
  const float* X = (z == 0) ? xq : (z == 1) ? xk : xv;
  const float* W = (z == 0) ? wq : (z == 1) ? wk : wv;
  const float* bias = (z == 0) ? bq : (z == 1) ? bk : bv;
  unsigned short* out = (z == 0) ? Qh : (z == 1) ? Kh : Vh;
  const float scale = (z == 0) ? (0.125f * 1.44269504088896340736f) : 1.0f;

  __shared__ unsigned short As[128][48];  // 128x32 bf16, pad to 48 (96B rows, 16B-aligned)
  __shared__ unsigned short Bs[128][48];

  const int tid = threadIdx.x;
  const int rowBase = blockIdx.x * 128;
  const int colBase = blockIdx.y * 128;
  const int lane = tid & 63;
  const int w = tid >> 6;
  const int wr = (w >> 1) * 64;
  const int wc = (w & 1) * 64;
  const int l15 = lane & 15;
  const int quad = lane >> 4;

  const f32x4 zero4 = {0.f, 0.f, 0.f, 0.f};
  f32x4 acc[4][4];
  #pragma unroll
  for (int i = 0; i < 4; ++i)
    #pragma unroll
    for (int j = 0; j < 4; ++j) acc[i][j] = zero4;

  for (int kt = 0; kt < ND; kt += 32) {
    __syncthreads();
    #pragma unroll
    for (int t = 0; t < 4; ++t) {
      int f = tid + t * 256;       // 0..1023
      int row = f >> 3;            // 0..127
      int c = (f & 7) * 4;         // 0..28
      float4 a = *(const float4*)(X + (size_t)(rowBase + row) * ND + kt + c);
      float4 b = *(const float4*)(W + (size_t)(colBase + row) * ND + kt + c);
      ushort4 ua, ub;
      ua.x = f2bf(a.x); ua.y = f2bf(a.y); ua.z = f2bf(a.z); ua.w = f2bf(a.w);
      ub.x = f2bf(b.x); ub.y = f2bf(b.y); ub.z = f2bf(b.z); ub.w = f2bf(b.w);
      *(ushort4*)&As[row][c] = ua;
      *(ushort4*)&Bs[row][c] = ub;
    }
    __syncthreads();
    bf16x8 af[4], bf[4];
    #pragma unroll
    for (int i = 0; i < 4; ++i) af[i] = *(const bf16x8*)&As[wr + i * 16 + l15][quad * 8];
    #pragma unroll
    for (int j = 0; j < 4; ++j) bf[j] = *(const bf16x8*)&Bs[wc + j * 16 + l15][quad * 8];
    #pragma unroll
    for (int i = 0; i < 4; ++i)
      #pragma unroll
      for (int j = 0; j < 4; ++j)
        acc[i][j] = __builtin_amdgcn_mfma_f32_16x16x32_bf16(af[i], bf[j], acc[i][j], 0, 0, 0);
  }

  #pragma unroll
  for (int i = 0; i < 4; ++i) {
    #pragma unroll
    for (int j = 0; j < 4; ++j) {
      int colg = colBase + wc + j * 16 + l15;
      float bval = bias[colg];
      #pragma unroll
      for (int r = 0; r < 4; ++r) {
        int rowg = rowBase + wr + i * 16 + quad * 4 + r;
        float val = (acc[i][j][r] + bval) * scale;
        int b_ = rowg >> 11;       // / NS
        int s_ = rowg & (NS - 1);
        int h_ = colg >> 6;
        int d_ = colg & 63;
        out[(((size_t)(b_ * NH + h_) * NS) + s_) * NDH + d_] = f2bf(val);
      }
    }
  }
}

// ---------------------------------------------------------------------------
// Vh [B,H,S,DH] -> Vht [B,H,DH,S]  (64x64 LDS-tiled transpose, both sides coalesced)
// ---------------------------------------------------------------------------
__global__ __launch_bounds__(256) void transpose_v(
    const unsigned short* __restrict__ Vh, unsigned short* __restrict__ Vht)
{
  __shared__ unsigned short tile[64][72];
  const int bh = blockIdx.y;
  const int s0 = blockIdx.x * 64;
  const int tid = threadIdx.x;
  {
    int row = tid >> 2;
    int c = (tid & 3) * 16;
    const unsigned short* src = Vh + ((size_t)bh * NS + s0 + row) * NDH + c;
    *(bf16x8*)&tile[row][c] = *(const bf16x8*)src;
    *(bf16x8*)&tile[row][c + 8] = *(const bf16x8*)(src + 8);
  }
  __syncthreads();
  {
    int d = tid >> 2;
    int seg = (tid & 3) * 16;
    unsigned short tmp[16];
    #pragma unroll
    for (int i = 0; i < 16; ++i) tmp[i] = tile[seg + i][d];
    unsigned short* dst = Vht + ((size_t)bh * NDH + d) * NS + s0 + seg;
    *(bf16x8*)dst = *(bf16x8*)&tmp[0];
    *(bf16x8*)(dst + 8) = *(bf16x8*)&tmp[8];
  }
}

// ---------------------------------------------------------------------------
// Flash attention, causal. Block = 4 waves, 64 q-rows (16 per wave), 128-key
// tiles. Online softmax in fp32 (exp2 domain; scale folded into Q). P goes
// C-layout -> LDS -> A-layout for PV. Output ctx bf16 [B,S,D].
// ---------------------------------------------------------------------------
__global__ __launch_bounds__(256) void attn(
    const unsigned short* __restrict__ Qh, const unsigned short* __restrict__ Kh,
    const unsigned short* __restrict__ Vht, unsigned short* __restrict__ ctx)
{
  __shared__ unsigned short Qs[64][72];
  __shared__ unsigned short Ks[128][72];
  __shared__ unsigned short Vts[64][136];
  __shared__ unsigned short Ps[64][136];

  const int bh = blockIdx.y;
  const int b_ = bh >> 4;
  const int h_ = bh & 15;
  const int t = (int)gridDim.x - 1 - (int)blockIdx.x;  // heavy tiles first
  const int qb0 = t * 64;

  const int tid = threadIdx.x;
  const int lane = tid & 63;
  const int w = tid >> 6;
  const int l15 = lane & 15;
  const int quad = lane >> 4;

  {
    int row = tid >> 2;
    int seg = (tid & 3) * 16;
    const unsigned short* src = Qh + ((size_t)bh * NS + qb0 + row) * NDH + seg;
    *(bf16x8*)&Qs[row][seg] = *(const bf16x8*)src;
    *(bf16x8*)&Qs[row][seg + 8] = *(const bf16x8*)(src + 8);
  }

  const f32x4 zero4 = {0.f, 0.f, 0.f, 0.f};
  f32x4 o[4];
  #pragma unroll
  for (int n = 0; n < 4; ++n) o[n] = zero4;
  float mrow[4], lrow[4];
  #pragma unroll
  for (int r = 0; r < 4; ++r) { mrow[r] = -1e30f; lrow[r] = 0.f; }

  const int numK = (qb0 + 63) / 128 + 1;
  for (int it = 0; it < numK; ++it) {
    const int kb = it * 128;
    __syncthreads();
    {
      int row = tid >> 1;
      int seg = (tid & 1) * 32;
      const unsigned short* src = Kh + ((size_t)bh * NS + kb + row) * NDH + seg;
      #pragma unroll
      for (int u = 0; u < 4; ++u)
        *(bf16x8*)&Ks[row][seg + u * 8] = *(const bf16x8*)(src + u * 8);
    }
    {
      int row = tid >> 2;
      int seg = (tid & 3) * 32;
      const unsigned short* src = Vht + ((size_t)bh * NDH + row) * NS + kb + seg;
      #pragma unroll
      for (int u = 0; u < 4; ++u)
        *(bf16x8*)&Vts[row][seg + u * 8] = *(const bf16x8*)(src + u * 8);
    }
    __syncthreads();

    // S = Q K^T (already in exp2 domain)
    f32x4 s[8];
    #pragma unroll
    for (int j = 0; j < 8; ++j) s[j] = zero4;
    bf16x8 aq0 = *(const bf16x8*)&Qs[w * 16 + l15][quad * 8];
    bf16x8 aq1 = *(const bf16x8*)&Qs[w * 16 + l15][32 + quad * 8];
    #pragma unroll
    for (int j = 0; j < 8; ++j) {
      bf16x8 bk0 = *(const bf16x8*)&Ks[j * 16 + l15][quad * 8];
      bf16x8 bk1 = *(const bf16x8*)&Ks[j * 16 + l15][32 + quad * 8];
      s[j] = __builtin_amdgcn_mfma_f32_16x16x32_bf16(aq0, bk0, s[j], 0, 0, 0);
      s[j] = __builtin_amdgcn_mfma_f32_16x16x32_bf16(aq1, bk1, s[j], 0, 0, 0);
    }

    if (it == numK - 1) {   // only the last tile can contain masked entries
      #pragma unroll
      for (int j = 0; j < 8; ++j) {
        int key = kb + j * 16 + l15;
        #pragma unroll
        for (int r = 0; r < 4; ++r) {
          int q = qb0 + w * 16 + quad * 4 + r;
          if (key > q) s[j][r] = -1e30f;
        }
      }
    }

    // online softmax (rows quad*4+r, reduced across the quad's 16 lanes)
    float alpha[4];
    #pragma unroll
    for (int r = 0; r < 4; ++r) {
      float mx = s[0][r];
      #pragma unroll
      for (int j = 1; j < 8; ++j) mx = fmaxf(mx, s[j][r]);
      mx = fmaxf(mx, __shfl_xor(mx, 1, 16));
      mx = fmaxf(mx, __shfl_xor(mx, 2, 16));
      mx = fmaxf(mx, __shfl_xor(mx, 4, 16));
      mx = fmaxf(mx, __shfl_xor(mx, 8, 16));
      float mn = fmaxf(mrow[r], mx);
      alpha[r] = exp2f(mrow[r] - mn);
      mrow[r] = mn;
      float sum = 0.f;
      #pragma unroll
      for (int j = 0; j < 8; ++j) {
        float p = exp2f(s[j][r] - mn);
        s[j][r] = p;
        sum += p;
      }
      sum += __shfl_xor(sum, 1, 16);
      sum += __shfl_xor(sum, 2, 16);
      sum += __shfl_xor(sum, 4, 16);
      sum += __shfl_xor(sum, 8, 16);
      lrow[r] = lrow[r] * alpha[r] + sum;
    }

    // P (C-layout) -> LDS bf16
    #pragma unroll
    for (int j = 0; j < 8; ++j)
      #pragma unroll
      for (int r = 0; r < 4; ++r)
        Ps[w * 16 + quad * 4 + r][j * 16 + l15] = f2bf(s[j][r]);

    #pragma unroll
    for (int n = 0; n < 4; ++n)
      #pragma unroll
      for (int r = 0; r < 4; ++r) o[n][r] *= alpha[r];

    __syncthreads();  // Ps visible (cross-lane within wave; barrier is cheap + safe)

    // O += P V  (A from Ps, B from Vts[d][key])
    #pragma unroll
    for (int ks = 0; ks < 4; ++ks) {
      bf16x8 ap = *(const bf16x8*)&Ps[w * 16 + l15][ks * 32 + quad * 8];
      #pragma unroll
      for (int n = 0; n < 4; ++n) {
        bf16x8 bv8 = *(const bf16x8*)&Vts[n * 16 + l15][ks * 32 + quad * 8];
        o[n] = __builtin_amdgcn_mfma_f32_16x16x32_bf16(ap, bv8, o[n], 0, 0, 0);
      }
    }
  }

  #pragma unroll
  for (int n = 0; n < 4; ++n) {
    #pragma unroll
    for (int r = 0; r < 4; ++r) {
      int q = qb0 + w * 16 + quad * 4 + r;
      int d = n * 16 + l15;
      float val = o[n][r] / lrow[r];
      ctx[((size_t)b_ * NS + q) * ND + h_ * NDH + d] = f2bf(val);
    }
  }
}

// ---------------------------------------------------------------------------
// Output projection: out = ctx(bf16) @ wo^T + bo, fp32 row-major into d_out
// ---------------------------------------------------------------------------
__global__ __launch_bounds__(256) void gemm_out(
    const unsigned short* __restrict__ ctx, const float* __restrict__ wo,
    const float* __restrict__ bo, float* __restrict__ out)
{
  __shared__ unsigned short As[128][48];
  __shared__ unsigned short Bs[128][48];

  const int tid = threadIdx.x;
  const int rowBase = blockIdx.x * 128;
  const int colBase = blockIdx.y * 128;
  const int lane = tid & 63;
  const int w = tid >> 6;
  const int wr = (w >> 1) * 64;
  const int wc = (w & 1) * 64;
  const int l15 = lane & 15;
  const int quad = lane >> 4;

  const f32x4 zero4 = {0.f, 0.f, 0.f, 0.f};
  f32x4 acc[4][4];
  #pragma unroll
  for (int i = 0; i < 4; ++i)
    #pragma unroll
    for (int j = 0; j < 4; ++j) acc[i][j] = zero4;

  for (int kt = 0; kt < ND; kt += 32) {
    __syncthreads();
    #pragma unroll
    for (int t = 0; t < 2; ++t) {
      int f = tid + t * 256;       // 0..511
      int row = f >> 2;            // 0..127
      int c8 = (f & 3) * 8;        // 0,8,16,24
      *(bf16x8*)&As[row][c8] =
          *(const bf16x8*)(ctx + (size_t)(rowBase + row) * ND + kt + c8);
    }
    #pragma unroll
    for (int t = 0; t < 4; ++t) {
      int f = tid + t * 256;
      int row = f >> 3;
      int c = (f & 7) * 4;
      float4 b = *(const float4*)(wo + (size_t)(colBase + row) * ND + kt + c);
      ushort4 ub;
      ub.x = f2bf(b.x); ub.y = f2bf(b.y); ub.z = f2bf(b.z); ub.w = f2bf(b.w);
      *(ushort4*)&Bs[row][c] = ub;
    }
    __syncthreads();
    bf16x8 af[4], bf[4];
    #pragma unroll
    for (int i = 0; i < 4; ++i) af[i] = *(const bf16x8*)&As[wr + i * 16 + l15][quad * 8];
    #pragma unroll
    for (int j = 0; j < 4; ++j) bf[j] = *(const bf16x8*)&Bs[wc + j * 16 + l15][quad * 8];
    #pragma unroll
    for (int i = 0; i < 4; ++i)
      #pragma unroll
      for (int j = 0; j < 4; ++j)
        acc[i][j] = __builtin_amdgcn_mfma_f32_16x16x32_bf16(af[i], bf[j], acc[i][j], 0, 0, 0);
  }

  #pragma unroll
  for (int i = 0; i < 4; ++i) {
    #pragma unroll
    for (int j = 0; j < 4; ++j) {
      int colg = colBase + wc + j * 16 + l15;
      float bval = bo[colg];
      #pragma unroll
      for (int r = 0; r < 4; ++r) {
        int rowg = rowBase + wr + i * 16 + quad * 4 + r;
        out[(size_t)rowg * ND + colg] = acc[i][j][r] + bval;
      }
    }
  }
}

extern "C" void kernel_launch(void* const* d_in, const int* in_sizes, int n_in,
                              void* d_out, int out_size, void* d_ws, size_t ws_size,
                              hipStream_t stream) {
  const float* q  = (const float*)d_in[0];
  const float* k  = (const float*)d_in[1];
  const float* v  = (const float*)d_in[2];
  // d_in[3] = mask (causal by construction; not needed)
  const float* wq = (const float*)d_in[4];
  const float* bq = (const float*)d_in[5];
  const float* wk = (const float*)d_in[6];
  const float* bk = (const float*)d_in[7];
  const float* wv = (const float*)d_in[8];
  const float* bv = (const float*)d_in[9];
  const float* wo = (const float*)d_in[10];
  const float* bo = (const float*)d_in[11];
  float* out = (float*)d_out;

  unsigned short* ws = (unsigned short*)d_ws;
  const size_t E = (size_t)NB * NH * NS * NDH;  // 8,388,608 elements
  unsigned short* Qh  = ws;
  unsigned short* Kh  = ws + E;
  unsigned short* Vh  = ws + 2 * E;
  unsigned short* Vht = ws + 3 * E;
  unsigned short* ctx = Vh;  // Vh dead after transpose_v; reuse for ctx

  gemm_qkv<<<dim3(64, 8, 3), 256, 0, stream>>>(q, k, v, wq, wk, wv, bq, bk, bv, Qh, Kh, Vh);
  transpose_v<<<dim3(NS / 64, NB * NH), 256, 0, stream>>>(Vh, Vht);
  attn<<<dim3(NS / 64, NB * NH), 256, 0, stream>>>(Qh, Kh, Vht, ctx);
  gemm_out<<<dim3(64, 8), 256, 0, stream>>>(ctx, wo, bo, out);
}

// Round 2
// 448.730 us; speedup vs baseline: 1.3055x; 1.3055x over previous
//
#include <hip/hip_runtime.h>
#include <hip/hip_bf16.h>

#define NB 4
#define NS 2048
#define ND 1024
#define NH 16
#define NDH 64
#define E_ 8388608   // NB*NS*ND == NB*NH*NS*NDH
#define W_ 1048576   // ND*ND

typedef __attribute__((ext_vector_type(8))) __bf16 bf16x8;
typedef __attribute__((ext_vector_type(4))) float f32x4;
typedef unsigned short us16;

__device__ __forceinline__ unsigned short f2bf(float f) {
  union { float f; unsigned u; } v; v.f = f;
  unsigned r = v.u + 0x7FFFu + ((v.u >> 16) & 1u);
  return (unsigned short)(r >> 16);
}

typedef const __attribute__((address_space(1))) unsigned int* gas_t;
typedef __attribute__((address_space(3))) unsigned int* las_t;
__device__ __forceinline__ void gl2lds16(const void* g, void* l) {
  __builtin_amdgcn_global_load_lds((gas_t)g, (las_t)l, 16, 0, 0);
}

// ---------------------------------------------------------------------------
// fp32 -> bf16 conversion pass: q,k,v (8.39M each) + wq,wk,wv,wo (1.05M each)
// ---------------------------------------------------------------------------
__global__ __launch_bounds__(256) void conv_bf16(
    const float* __restrict__ q, const float* __restrict__ k, const float* __restrict__ v,
    const float* __restrict__ wq, const float* __restrict__ wk, const float* __restrict__ wv,
    const float* __restrict__ wo,
    us16* __restrict__ qb, us16* __restrict__ kb, us16* __restrict__ vb,
    us16* __restrict__ wqb, us16* __restrict__ wkb, us16* __restrict__ wvb,
    us16* __restrict__ wob)
{
  int b = blockIdx.x;
  int seg, off;
  if (b < 24576) { seg = b >> 13; off = b & 8191; }
  else { b -= 24576; seg = 3 + (b >> 10); off = b & 1023; }
  const float* s; us16* d;
  switch (seg) {
    case 0: s = q;  d = qb;  break;
    case 1: s = k;  d = kb;  break;
    case 2: s = v;  d = vb;  break;
    case 3: s = wq; d = wqb; break;
    case 4: s = wk; d = wkb; break;
    case 5: s = wv; d = wvb; break;
    default: s = wo; d = wob; break;
  }
  size_t idx = ((size_t)off * 256 + threadIdx.x) * 4;
  float4 f = *(const float4*)(s + idx);
  ushort4 u;
  u.x = f2bf(f.x); u.y = f2bf(f.y); u.z = f2bf(f.z); u.w = f2bf(f.w);
  *(ushort4*)(d + idx) = u;
}

// ---------------------------------------------------------------------------
// Projection GEMM (bf16 x bf16): Y = X @ W^T + bias, scatter to [B,H,S,DH]
// m97-style: 128x128 tile, BK=64, global_load_lds width-16, unpadded LDS.
// ---------------------------------------------------------------------------
__global__ __launch_bounds__(256) void gemm_proj(
    const us16* __restrict__ A, const us16* __restrict__ Wt,
    const float* __restrict__ bias, us16* __restrict__ out, float scale)
{
  __shared__ us16 As[128][64];
  __shared__ us16 Bs[128][64];
  const int tid = threadIdx.x;
  const int lane = tid & 63;
  const int w = tid >> 6;
  const int l15 = lane & 15, quad = lane >> 4;
  const int rowBase = blockIdx.x * 128, colBase = blockIdx.y * 128;
  const int srow = w * 32 + (lane >> 3);
  const int scol = (lane & 7) * 8;
  const us16* ga = A  + (size_t)(rowBase + srow) * ND + scol;
  const us16* gb = Wt + (size_t)(colBase + srow) * ND + scol;
  const int wr = (w >> 1) * 64, wc = (w & 1) * 64;

  f32x4 acc[4][4] = {};
  for (int kt = 0; kt < ND; kt += 64) {
    __syncthreads();
    #pragma unroll
    for (int c = 0; c < 4; ++c) {
      gl2lds16(ga + kt + c * 8 * ND, &As[w * 32 + c * 8][0]);
      gl2lds16(gb + kt + c * 8 * ND, &Bs[w * 32 + c * 8][0]);
    }
    __syncthreads();
    #pragma unroll
    for (int ks = 0; ks < 2; ++ks) {
      bf16x8 af[4], bfr[4];
      #pragma unroll
      for (int i = 0; i < 4; ++i) af[i]  = *(const bf16x8*)&As[wr + i * 16 + l15][ks * 32 + quad * 8];
      #pragma unroll
      for (int j = 0; j < 4; ++j) bfr[j] = *(const bf16x8*)&Bs[wc + j * 16 + l15][ks * 32 + quad * 8];
      #pragma unroll
      for (int i = 0; i < 4; ++i)
        #pragma unroll
        for (int j = 0; j < 4; ++j)
          acc[i][j] = __builtin_amdgcn_mfma_f32_16x16x32_bf16(af[i], bfr[j], acc[i][j], 0, 0, 0);
    }
  }

  #pragma unroll
  for (int i = 0; i < 4; ++i) {
    #pragma unroll
    for (int j = 0; j < 4; ++j) {
      int colg = colBase + wc + j * 16 + l15;
      float bval = bias[colg];
      int h_ = colg >> 6, d_ = colg & 63;
      #pragma unroll
      for (int r = 0; r < 4; ++r) {
        int rowg = rowBase + wr + i * 16 + quad * 4 + r;
        int b_ = rowg >> 11, s_ = rowg & (NS - 1);
        out[(((size_t)(b_ * NH + h_) * NS) + s_) * NDH + d_] = f2bf((acc[i][j][r] + bval) * scale);
      }
    }
  }
}

// ---------------------------------------------------------------------------
// Vh [B,H,S,DH] -> Vht [B,H,DH,S]
// ---------------------------------------------------------------------------
__global__ __launch_bounds__(256) void transpose_v(
    const us16* __restrict__ Vh, us16* __restrict__ Vht)
{
  __shared__ us16 tile[64][72];
  const int bh = blockIdx.y;
  const int s0 = blockIdx.x * 64;
  const int tid = threadIdx.x;
  {
    int row = tid >> 2;
    int c = (tid & 3) * 16;
    const us16* src = Vh + ((size_t)bh * NS + s0 + row) * NDH + c;
    *(bf16x8*)&tile[row][c] = *(const bf16x8*)src;
    *(bf16x8*)&tile[row][c + 8] = *(const bf16x8*)(src + 8);
  }
  __syncthreads();
  {
    int d = tid >> 2;
    int seg = (tid & 3) * 16;
    us16 tmp[16];
    #pragma unroll
    for (int i = 0; i < 16; ++i) tmp[i] = tile[seg + i][d];
    us16* dst = Vht + ((size_t)bh * NDH + d) * NS + s0 + seg;
    *(bf16x8*)dst = *(bf16x8*)&tmp[0];
    *(bf16x8*)(dst + 8) = *(bf16x8*)&tmp[8];
  }
}

// ---------------------------------------------------------------------------
// Flash attention, causal, fixed-max softmax (exp2 domain, scale folded in Q).
// 64 q-rows/block (16/wave), 64-key tiles, l via ones-MFMA, Ps wave-private.
// ---------------------------------------------------------------------------
__global__ __launch_bounds__(256, 4) void attn(
    const us16* __restrict__ Qh, const us16* __restrict__ Kh,
    const us16* __restrict__ Vht, us16* __restrict__ ctx)
{
  __shared__ us16 Qs[64][64];
  __shared__ us16 Ks[64][64];
  __shared__ us16 Vts[64][64];
  __shared__ us16 Ps[64][72];

  const int bh = blockIdx.y, b_ = bh >> 4, h_ = bh & 15;
  const int qb0 = ((int)gridDim.x - 1 - (int)blockIdx.x) * 64;  // heavy tiles first
  const int tid = threadIdx.x, lane = tid & 63, w = tid >> 6;
  const int l15 = lane & 15, quad = lane >> 4;
  const int srow8 = lane >> 3, scol = (lane & 7) * 8;

  const us16* gq = Qh + ((size_t)bh * NS + qb0 + w * 16 + srow8) * NDH + scol;
  gl2lds16(gq, &Qs[w * 16][0]);
  gl2lds16(gq + 8 * NDH, &Qs[w * 16 + 8][0]);

  f32x4 o[4] = {};
  f32x4 o_l = {};
  bf16x8 ones;
  #pragma unroll
  for (int i = 0; i < 8; ++i) ones[i] = (__bf16)1.0f;

  __syncthreads();
  bf16x8 aq0 = *(const bf16x8*)&Qs[w * 16 + l15][quad * 8];
  bf16x8 aq1 = *(const bf16x8*)&Qs[w * 16 + l15][32 + quad * 8];

  const int nt = qb0 / 64 + 1;
  const us16* gk = Kh  + ((size_t)bh * NS + w * 16 + srow8) * NDH + scol;
  const us16* gv = Vht + ((size_t)bh * NDH + w * 16 + srow8) * NS + scol;

  for (int it = 0; it < nt; ++it) {
    const int kb = it * 64;
    __syncthreads();
    gl2lds16(gk + (size_t)kb * NDH,        &Ks[w * 16][0]);
    gl2lds16(gk + (size_t)(kb + 8) * NDH,  &Ks[w * 16 + 8][0]);
    gl2lds16(gv + kb,                      &Vts[w * 16][0]);
    gl2lds16(gv + kb + 8 * NS,             &Vts[w * 16 + 8][0]);
    __syncthreads();

    f32x4 s[4] = {};
    #pragma unroll
    for (int j = 0; j < 4; ++j) {
      bf16x8 bk0 = *(const bf16x8*)&Ks[j * 16 + l15][quad * 8];
      bf16x8 bk1 = *(const bf16x8*)&Ks[j * 16 + l15][32 + quad * 8];
      s[j] = __builtin_amdgcn_mfma_f32_16x16x32_bf16(aq0, bk0, s[j], 0, 0, 0);
      s[j] = __builtin_amdgcn_mfma_f32_16x16x32_bf16(aq1, bk1, s[j], 0, 0, 0);
    }

    if (it == nt - 1) {  // diagonal tile: kb == qb0
      #pragma unroll
      for (int j = 0; j < 4; ++j) {
        int keyl = j * 16 + l15;
        #pragma unroll
        for (int r = 0; r < 4; ++r) {
          int ql = w * 16 + quad * 4 + r;
          if (keyl > ql) s[j][r] = -1e30f;
        }
      }
    }

    #pragma unroll
    for (int j = 0; j < 4; ++j)
      #pragma unroll
      for (int r = 0; r < 4; ++r) {
        float p = __builtin_amdgcn_exp2f(s[j][r]);
        Ps[w * 16 + quad * 4 + r][j * 16 + l15] = (us16)(__float_as_uint(p) >> 16);
      }

    // Ps rows [w*16, w*16+16) are wave-private: no barrier, lgkmcnt orders RAW.
    #pragma unroll
    for (int ch = 0; ch < 2; ++ch) {
      bf16x8 ap = *(const bf16x8*)&Ps[w * 16 + l15][ch * 32 + quad * 8];
      o_l = __builtin_amdgcn_mfma_f32_16x16x32_bf16(ap, ones, o_l, 0, 0, 0);
      #pragma unroll
      for (int n = 0; n < 4; ++n) {
        bf16x8 bv = *(const bf16x8*)&Vts[n * 16 + l15][ch * 32 + quad * 8];
        o[n] = __builtin_amdgcn_mfma_f32_16x16x32_bf16(ap, bv, o[n], 0, 0, 0);
      }
    }
  }

  #pragma unroll
  for (int r = 0; r < 4; ++r) {
    float inv = __builtin_amdgcn_rcpf(o_l[r]);
    int qg = qb0 + w * 16 + quad * 4 + r;
    us16* dst = ctx + ((size_t)b_ * NS + qg) * ND + h_ * NDH;
    #pragma unroll
    for (int n = 0; n < 4; ++n)
      dst[n * 16 + l15] = f2bf(o[n][r] * inv);
  }
}

// ---------------------------------------------------------------------------
// Output projection: out = ctx(bf16) @ wo^T(bf16) + bo, fp32 row-major
// ---------------------------------------------------------------------------
__global__ __launch_bounds__(256) void gemm_out(
    const us16* __restrict__ A, const us16* __restrict__ Wt,
    const float* __restrict__ bias, float* __restrict__ out)
{
  __shared__ us16 As[128][64];
  __shared__ us16 Bs[128][64];
  const int tid = threadIdx.x;
  const int lane = tid & 63;
  const int w = tid >> 6;
  const int l15 = lane & 15, quad = lane >> 4;
  const int rowBase = blockIdx.x * 128, colBase = blockIdx.y * 128;
  const int srow = w * 32 + (lane >> 3);
  const int scol = (lane & 7) * 8;
  const us16* ga = A  + (size_t)(rowBase + srow) * ND + scol;
  const us16* gb = Wt + (size_t)(colBase + srow) * ND + scol;
  const int wr = (w >> 1) * 64, wc = (w & 1) * 64;

  f32x4 acc[4][4] = {};
  for (int kt = 0; kt < ND; kt += 64) {
    __syncthreads();
    #pragma unroll
    for (int c = 0; c < 4; ++c) {
      gl2lds16(ga + kt + c * 8 * ND, &As[w * 32 + c * 8][0]);
      gl2lds16(gb + kt + c * 8 * ND, &Bs[w * 32 + c * 8][0]);
    }
    __syncthreads();
    #pragma unroll
    for (int ks = 0; ks < 2; ++ks) {
      bf16x8 af[4], bfr[4];
      #pragma unroll
      for (int i = 0; i < 4; ++i) af[i]  = *(const bf16x8*)&As[wr + i * 16 + l15][ks * 32 + quad * 8];
      #pragma unroll
      for (int j = 0; j < 4; ++j) bfr[j] = *(const bf16x8*)&Bs[wc + j * 16 + l15][ks * 32 + quad * 8];
      #pragma unroll
      for (int i = 0; i < 4; ++i)
        #pragma unroll
        for (int j = 0; j < 4; ++j)
          acc[i][j] = __builtin_amdgcn_mfma_f32_16x16x32_bf16(af[i], bfr[j], acc[i][j], 0, 0, 0);
    }
  }

  #pragma unroll
  for (int i = 0; i < 4; ++i) {
    #pragma unroll
    for (int j = 0; j < 4; ++j) {
      int colg = colBase + wc + j * 16 + l15;
      float bval = bias[colg];
      #pragma unroll
      for (int r = 0; r < 4; ++r) {
        int rowg = rowBase + wr + i * 16 + quad * 4 + r;
        out[(size_t)rowg * ND + colg] = acc[i][j][r] + bval;
      }
    }
  }
}

extern "C" void kernel_launch(void* const* d_in, const int* in_sizes, int n_in,
                              void* d_out, int out_size, void* d_ws, size_t ws_size,
                              hipStream_t stream) {
  const float* q  = (const float*)d_in[0];
  const float* k  = (const float*)d_in[1];
  const float* v  = (const float*)d_in[2];
  // d_in[3] = mask (causal by construction)
  const float* wq = (const float*)d_in[4];
  const float* bq = (const float*)d_in[5];
  const float* wk = (const float*)d_in[6];
  const float* bk = (const float*)d_in[7];
  const float* wv = (const float*)d_in[8];
  const float* bv = (const float*)d_in[9];
  const float* wo = (const float*)d_in[10];
  const float* bo = (const float*)d_in[11];

  us16* ws = (us16*)d_ws;
  us16* qb  = ws;             // -> later Kh
  us16* kb  = ws + (size_t)E_;        // -> later Vh
  us16* vb  = ws + (size_t)2 * E_;    // -> later ctx
  us16* wqb = ws + (size_t)3 * E_;
  us16* wkb = wqb + W_;
  us16* wvb = wkb + W_;
  us16* wob = wvb + W_;
  us16* Kh  = qb;
  us16* Vh  = kb;
  us16* ctx = vb;
  us16* Vht = (us16*)d_out;            // dead before gemm_out writes d_out
  us16* Qh  = (us16*)d_out + (size_t)E_;

  const float qscale = 0.125f * 1.44269504088896340736f;  // 1/sqrt(DH) * log2(e)

  conv_bf16<<<28672, 256, 0, stream>>>(q, k, v, wq, wk, wv, wo,
                                       qb, kb, vb, wqb, wkb, wvb, wob);
  gemm_proj<<<dim3(64, 8), 256, 0, stream>>>(qb, wqb, bq, Qh, qscale);
  gemm_proj<<<dim3(64, 8), 256, 0, stream>>>(kb, wkb, bk, Kh, 1.0f);
  gemm_proj<<<dim3(64, 8), 256, 0, stream>>>(vb, wvb, bv, Vh, 1.0f);
  transpose_v<<<dim3(NS / 64, NB * NH), 256, 0, stream>>>(Vh, Vht);
  attn<<<dim3(NS / 64, NB * NH), 256, 0, stream>>>(Qh, Kh, Vht, ctx);
  gemm_out<<<dim3(64, 8), 256, 0, stream>>>(ctx, wob, bo, (float*)d_out);
}

// Round 3
// 351.254 us; speedup vs baseline: 1.6678x; 1.2775x over previous
//
#include <hip/hip_runtime.h>
#include <hip/hip_bf16.h>

#define NB 4
#define NS 2048
#define ND 1024
#define NH 16
#define NDH 64
#define E_ 8388608   // NB*NS*ND
#define W_ 1048576   // ND*ND

typedef __attribute__((ext_vector_type(8))) __bf16 bf16x8;
typedef __attribute__((ext_vector_type(4))) float f32x4;
typedef __attribute__((ext_vector_type(2))) unsigned int u32x2;
typedef unsigned short us16;
typedef unsigned int u32;

__device__ __forceinline__ unsigned short f2bf(float f) {
  union { float f; unsigned u; } v; v.f = f;
  unsigned r = v.u + 0x7FFFu + ((v.u >> 16) & 1u);
  return (unsigned short)(r >> 16);
}

typedef const __attribute__((address_space(1))) unsigned int* gas_t;
typedef __attribute__((address_space(3))) unsigned int* las_t;
__device__ __forceinline__ void gl2lds16(const void* g, void* l) {
  __builtin_amdgcn_global_load_lds((gas_t)g, (las_t)l, 16, 0, 0);
}

// ---------------------------------------------------------------------------
// fp32 -> bf16 conversion pass
// ---------------------------------------------------------------------------
__global__ __launch_bounds__(256) void conv_bf16(
    const float* __restrict__ q, const float* __restrict__ k, const float* __restrict__ v,
    const float* __restrict__ wq, const float* __restrict__ wk, const float* __restrict__ wv,
    const float* __restrict__ wo,
    us16* __restrict__ qb, us16* __restrict__ kb, us16* __restrict__ vb,
    us16* __restrict__ wqb, us16* __restrict__ wkb, us16* __restrict__ wvb,
    us16* __restrict__ wob)
{
  int b = blockIdx.x;
  int seg, off;
  if (b < 24576) { seg = b >> 13; off = b & 8191; }
  else { b -= 24576; seg = 3 + (b >> 10); off = b & 1023; }
  const float* s; us16* d;
  switch (seg) {
    case 0: s = q;  d = qb;  break;
    case 1: s = k;  d = kb;  break;
    case 2: s = v;  d = vb;  break;
    case 3: s = wq; d = wqb; break;
    case 4: s = wk; d = wkb; break;
    case 5: s = wv; d = wvb; break;
    default: s = wo; d = wob; break;
  }
  size_t idx = ((size_t)off * 256 + threadIdx.x) * 4;
  float4 f = *(const float4*)(s + idx);
  ushort4 u;
  u.x = f2bf(f.x); u.y = f2bf(f.y); u.z = f2bf(f.z); u.w = f2bf(f.w);
  *(ushort4*)(d + idx) = u;
}

// ---------------------------------------------------------------------------
// Projection GEMM (bf16): Y = X @ W^T + bias.
// mode 0: Q -> [B,H,S,DH], scaled by qscale
// mode 1: K -> [B,H,S,DH]
// mode 2: V -> [B,H,DH,S] (transposed write, packed ushort4 over s)
// XOR-swizzled LDS: 16B unit u of row r stored at u^(r&7).
// ---------------------------------------------------------------------------
__global__ __launch_bounds__(256, 3) void gemm_proj(
    const us16* __restrict__ A, const us16* __restrict__ Wt,
    const float* __restrict__ bias, us16* __restrict__ out, float scale, int mode)
{
  __shared__ us16 As[128][64];
  __shared__ us16 Bs[128][64];
  const int tid = threadIdx.x;
  const int lane = tid & 63;
  const int w = tid >> 6;
  const int l15 = lane & 15, quad = lane >> 4;
  const int sw = l15 & 7;
  const int rowBase = blockIdx.x * 128, colBase = blockIdx.y * 128;
  const int srow = w * 32 + (lane >> 3);
  const int cu = (lane & 7) ^ ((lane >> 3) & 7);   // swizzled global 16B-unit
  const us16* ga = A  + (size_t)(rowBase + srow) * ND + cu * 8;
  const us16* gb = Wt + (size_t)(colBase + srow) * ND + cu * 8;
  const int wr = (w >> 1) * 64, wc = (w & 1) * 64;

  f32x4 acc[4][4] = {};
  for (int kt = 0; kt < ND; kt += 64) {
    __syncthreads();
    #pragma unroll
    for (int c = 0; c < 4; ++c) {
      gl2lds16(ga + kt + c * 8 * ND, &As[w * 32 + c * 8][0]);
      gl2lds16(gb + kt + c * 8 * ND, &Bs[w * 32 + c * 8][0]);
    }
    __syncthreads();
    #pragma unroll
    for (int ks = 0; ks < 2; ++ks) {
      bf16x8 af[4], bfr[4];
      #pragma unroll
      for (int i = 0; i < 4; ++i)
        af[i]  = *(const bf16x8*)&As[wr + i * 16 + l15][((ks * 4 + quad) ^ sw) * 8];
      #pragma unroll
      for (int j = 0; j < 4; ++j)
        bfr[j] = *(const bf16x8*)&Bs[wc + j * 16 + l15][((ks * 4 + quad) ^ sw) * 8];
      #pragma unroll
      for (int i = 0; i < 4; ++i)
        #pragma unroll
        for (int j = 0; j < 4; ++j)
          acc[i][j] = __builtin_amdgcn_mfma_f32_16x16x32_bf16(af[i], bfr[j], acc[i][j], 0, 0, 0);
    }
  }

  if (mode < 2) {
    #pragma unroll
    for (int i = 0; i < 4; ++i) {
      #pragma unroll
      for (int j = 0; j < 4; ++j) {
        int colg = colBase + wc + j * 16 + l15;
        float bval = bias[colg];
        int h_ = colg >> 6, d_ = colg & 63;
        #pragma unroll
        for (int r = 0; r < 4; ++r) {
          int rowg = rowBase + wr + i * 16 + quad * 4 + r;
          int b_ = rowg >> 11, s_ = rowg & (NS - 1);
          out[(((size_t)(b_ * NH + h_) * NS) + s_) * NDH + d_] = f2bf((acc[i][j][r] + bval) * scale);
        }
      }
    }
  } else {
    #pragma unroll
    for (int i = 0; i < 4; ++i) {
      #pragma unroll
      for (int j = 0; j < 4; ++j) {
        int colg = colBase + wc + j * 16 + l15;
        float bval = bias[colg];
        int h_ = colg >> 6, d_ = colg & 63;
        int rowg0 = rowBase + wr + i * 16 + quad * 4;
        int b_ = rowg0 >> 11, s0 = rowg0 & (NS - 1);
        ushort4 vv;
        vv.x = f2bf(acc[i][j][0] + bval);
        vv.y = f2bf(acc[i][j][1] + bval);
        vv.z = f2bf(acc[i][j][2] + bval);
        vv.w = f2bf(acc[i][j][3] + bval);
        *(ushort4*)(out + ((size_t)(b_ * NH + h_) * NDH + d_) * NS + s0) = vv;
      }
    }
  }
}

// ---------------------------------------------------------------------------
// Flash attention, causal, fixed-max softmax (exp2 domain; scale folded in Q).
// 128 q/block (32/wave), 64-key tiles. S^T = K·Q^T so P^T packs to b64 LDS
// writes; PV reads Ps as A-layout b128 (136-pad => optimal 8-way grouping).
// Ks/Vts XOR-swizzled. Denominator: per-lane scalar accum + end shuffles.
// ---------------------------------------------------------------------------
__global__ __launch_bounds__(256, 3) void attn(
    const us16* __restrict__ Qh, const us16* __restrict__ Kh,
    const us16* __restrict__ Vht, us16* __restrict__ ctx)
{
  __shared__ us16 Ks[64][64];
  __shared__ us16 Vts[64][64];
  __shared__ us16 Ps[4][32][136];
  us16* Qs = &Ps[0][0][0];   // Q staging overlays Ps (dead before first Ps write)

  const int bh = blockIdx.y, b_ = bh >> 4, h_ = bh & 15;
  const int qb0 = ((int)gridDim.x - 1 - (int)blockIdx.x) * 128;  // heavy first
  const int tid = threadIdx.x, lane = tid & 63, w = tid >> 6;
  const int l15 = lane & 15, quad = lane >> 4;
  const int sw = l15 & 7;
  const int lr8 = lane >> 3;                     // staging row within 8-chunk
  const int cu = (lane & 7) ^ (lr8 & 7);         // swizzled global 16B-unit

  // stage Q [128][64] (unswizzled; read once)
  {
    const us16* gq = Qh + ((size_t)bh * NS + qb0 + w * 32 + lr8) * NDH + (lane & 7) * 8;
    #pragma unroll
    for (int u = 0; u < 4; ++u)
      gl2lds16(gq + u * 8 * NDH, Qs + (w * 32 + u * 8) * 64);
  }
  __syncthreads();
  bf16x8 bq[2][2];
  #pragma unroll
  for (int ntl = 0; ntl < 2; ++ntl)
    #pragma unroll
    for (int c = 0; c < 2; ++c)
      bq[ntl][c] = *(const bf16x8*)(Qs + (w * 32 + ntl * 16 + l15) * 64 + c * 32 + quad * 8);

  f32x4 o[2][4] = {};
  float lsum[2] = {0.f, 0.f};
  const int qw = qb0 + w * 32;
  const int qg0 = qw + l15, qg1 = qw + 16 + l15;

  const us16* gk = Kh  + ((size_t)bh * NS + w * 16 + lr8) * NDH + cu * 8;
  const us16* gv = Vht + ((size_t)bh * NDH + w * 16 + lr8) * NS + cu * 8;

  const int nt = qb0 / 64 + 2;
  for (int it = 0; it < nt; ++it) {
    const int kb = it * 64;
    __syncthreads();
    gl2lds16(gk + (size_t)kb * NDH,           &Ks[w * 16][0]);
    gl2lds16(gk + (size_t)(kb + 8) * NDH,     &Ks[w * 16 + 8][0]);
    gl2lds16(gv + kb,                         &Vts[w * 16][0]);
    gl2lds16(gv + kb + 8 * NS,                &Vts[w * 16 + 8][0]);
    __syncthreads();

    if (kb <= qw + 31) {
      const bool full = (kb + 63 <= qw);
      #pragma unroll
      for (int mt = 0; mt < 4; ++mt) {
        bf16x8 ak0 = *(const bf16x8*)&Ks[mt * 16 + l15][(quad ^ sw) * 8];
        bf16x8 ak1 = *(const bf16x8*)&Ks[mt * 16 + l15][((4 + quad) ^ sw) * 8];
        #pragma unroll
        for (int ntl = 0; ntl < 2; ++ntl) {
          f32x4 s = {};
          s = __builtin_amdgcn_mfma_f32_16x16x32_bf16(ak0, bq[ntl][0], s, 0, 0, 0);
          s = __builtin_amdgcn_mfma_f32_16x16x32_bf16(ak1, bq[ntl][1], s, 0, 0, 0);
          u32 u[4];
          if (full) {
            #pragma unroll
            for (int r = 0; r < 4; ++r) {
              float p = __builtin_amdgcn_exp2f(s[r]);
              lsum[ntl] += p;
              u[r] = __float_as_uint(p);
            }
          } else {
            const int keyb = kb + mt * 16 + quad * 4;
            const int qg = ntl ? qg1 : qg0;
            #pragma unroll
            for (int r = 0; r < 4; ++r) {
              float p = (keyb + r <= qg) ? __builtin_amdgcn_exp2f(s[r]) : 0.f;
              lsum[ntl] += p;
              u[r] = __float_as_uint(p);
            }
          }
          u32 lo = (u[0] >> 16) | (u[1] & 0xffff0000u);
          u32 hi = (u[2] >> 16) | (u[3] & 0xffff0000u);
          *(u32x2*)&Ps[w][ntl * 16 + l15][mt * 16 + quad * 4] = (u32x2){lo, hi};
        }
      }
      // Ps rows are wave-private; compiler waitcnt orders the RAW.
      #pragma unroll
      for (int c = 0; c < 2; ++c) {
        bf16x8 bv[4];
        #pragma unroll
        for (int n = 0; n < 4; ++n)
          bv[n] = *(const bf16x8*)&Vts[n * 16 + l15][((c * 4 + quad) ^ sw) * 8];
        #pragma unroll
        for (int ntl = 0; ntl < 2; ++ntl) {
          bf16x8 ap = *(const bf16x8*)&Ps[w][ntl * 16 + l15][c * 32 + quad * 8];
          #pragma unroll
          for (int n = 0; n < 4; ++n)
            o[ntl][n] = __builtin_amdgcn_mfma_f32_16x16x32_bf16(ap, bv[n], o[ntl][n], 0, 0, 0);
        }
      }
    }
  }

  // reduce denominator across the 4 quads, then fetch per-row values
  #pragma unroll
  for (int ntl = 0; ntl < 2; ++ntl) {
    lsum[ntl] += __shfl_xor(lsum[ntl], 16, 64);
    lsum[ntl] += __shfl_xor(lsum[ntl], 32, 64);
  }
  #pragma unroll
  for (int ntl = 0; ntl < 2; ++ntl) {
    #pragma unroll
    for (int r = 0; r < 4; ++r) {
      float lrow = __shfl(lsum[ntl], quad * 4 + r, 64);
      float inv = __builtin_amdgcn_rcpf(lrow);
      int qg = qb0 + w * 32 + ntl * 16 + quad * 4 + r;
      us16* dst = ctx + ((size_t)b_ * NS + qg) * ND + h_ * NDH;
      #pragma unroll
      for (int n = 0; n < 4; ++n)
        dst[n * 16 + l15] = f2bf(o[ntl][n][r] * inv);
    }
  }
}

// ---------------------------------------------------------------------------
// Output projection: out = ctx(bf16) @ wo^T(bf16) + bo, fp32 row-major
// ---------------------------------------------------------------------------
__global__ __launch_bounds__(256, 3) void gemm_out(
    const us16* __restrict__ A, const us16* __restrict__ Wt,
    const float* __restrict__ bias, float* __restrict__ out)
{
  __shared__ us16 As[128][64];
  __shared__ us16 Bs[128][64];
  const int tid = threadIdx.x;
  const int lane = tid & 63;
  const int w = tid >> 6;
  const int l15 = lane & 15, quad = lane >> 4;
  const int sw = l15 & 7;
  const int rowBase = blockIdx.x * 128, colBase = blockIdx.y * 128;
  const int srow = w * 32 + (lane >> 3);
  const int cu = (lane & 7) ^ ((lane >> 3) & 7);
  const us16* ga = A  + (size_t)(rowBase + srow) * ND + cu * 8;
  const us16* gb = Wt + (size_t)(colBase + srow) * ND + cu * 8;
  const int wr = (w >> 1) * 64, wc = (w & 1) * 64;

  f32x4 acc[4][4] = {};
  for (int kt = 0; kt < ND; kt += 64) {
    __syncthreads();
    #pragma unroll
    for (int c = 0; c < 4; ++c) {
      gl2lds16(ga + kt + c * 8 * ND, &As[w * 32 + c * 8][0]);
      gl2lds16(gb + kt + c * 8 * ND, &Bs[w * 32 + c * 8][0]);
    }
    __syncthreads();
    #pragma unroll
    for (int ks = 0; ks < 2; ++ks) {
      bf16x8 af[4], bfr[4];
      #pragma unroll
      for (int i = 0; i < 4; ++i)
        af[i]  = *(const bf16x8*)&As[wr + i * 16 + l15][((ks * 4 + quad) ^ sw) * 8];
      #pragma unroll
      for (int j = 0; j < 4; ++j)
        bfr[j] = *(const bf16x8*)&Bs[wc + j * 16 + l15][((ks * 4 + quad) ^ sw) * 8];
      #pragma unroll
      for (int i = 0; i < 4; ++i)
        #pragma unroll
        for (int j = 0; j < 4; ++j)
          acc[i][j] = __builtin_amdgcn_mfma_f32_16x16x32_bf16(af[i], bfr[j], acc[i][j], 0, 0, 0);
    }
  }

  #pragma unroll
  for (int i = 0; i < 4; ++i) {
    #pragma unroll
    for (int j = 0; j < 4; ++j) {
      int colg = colBase + wc + j * 16 + l15;
      float bval = bias[colg];
      #pragma unroll
      for (int r = 0; r < 4; ++r) {
        int rowg = rowBase + wr + i * 16 + quad * 4 + r;
        out[(size_t)rowg * ND + colg] = acc[i][j][r] + bval;
      }
    }
  }
}

extern "C" void kernel_launch(void* const* d_in, const int* in_sizes, int n_in,
                              void* d_out, int out_size, void* d_ws, size_t ws_size,
                              hipStream_t stream) {
  const float* q  = (const float*)d_in[0];
  const float* k  = (const float*)d_in[1];
  const float* v  = (const float*)d_in[2];
  // d_in[3] = mask (causal by construction)
  const float* wq = (const float*)d_in[4];
  const float* bq = (const float*)d_in[5];
  const float* wk = (const float*)d_in[6];
  const float* bk = (const float*)d_in[7];
  const float* wv = (const float*)d_in[8];
  const float* bv = (const float*)d_in[9];
  const float* wo = (const float*)d_in[10];
  const float* bo = (const float*)d_in[11];

  us16* ws = (us16*)d_ws;
  us16* qb  = ws;                      // later reused as Kh
  us16* kb  = ws + (size_t)E_;
  us16* vb  = ws + (size_t)2 * E_;     // later reused as ctx
  us16* wqb = ws + (size_t)3 * E_;
  us16* wkb = wqb + W_;
  us16* wvb = wkb + W_;
  us16* wob = wvb + W_;
  us16* Kh  = qb;                      // K launch runs after Q launch read qb
  us16* ctx = vb;                      // attn runs after V launch read vb
  us16* Vht = (us16*)d_out;            // d_out scratch: dead before gemm_out
  us16* Qh  = (us16*)d_out + (size_t)E_;

  const float qscale = 0.125f * 1.44269504088896340736f;  // 1/sqrt(DH)*log2(e)

  conv_bf16<<<28672, 256, 0, stream>>>(q, k, v, wq, wk, wv, wo,
                                       qb, kb, vb, wqb, wkb, wvb, wob);
  gemm_proj<<<dim3(64, 8), 256, 0, stream>>>(qb, wqb, bq, Qh, qscale, 0);
  gemm_proj<<<dim3(64, 8), 256, 0, stream>>>(vb, wvb, bv, Vht, 1.0f, 2);
  gemm_proj<<<dim3(64, 8), 256, 0, stream>>>(kb, wkb, bk, Kh, 1.0f, 1);
  attn<<<dim3(NS / 128, NB * NH), 256, 0, stream>>>(Qh, Kh, Vht, ctx);
  gemm_out<<<dim3(64, 8), 256, 0, stream>>>(ctx, wob, bo, (float*)d_out);
}

// Round 4
// 319.870 us; speedup vs baseline: 1.8314x; 1.0981x over previous
//
#include <hip/hip_runtime.h>
#include <hip/hip_bf16.h>

#define NB 4
#define NS 2048
#define ND 1024
#define NH 16
#define NDH 64
#define E_ 8388608   // NB*NS*ND
#define W_ 1048576   // ND*ND

typedef __attribute__((ext_vector_type(8))) __bf16 bf16x8;
typedef __attribute__((ext_vector_type(4))) float f32x4;
typedef __attribute__((ext_vector_type(2))) unsigned int u32x2;
typedef unsigned short us16;
typedef unsigned int u32;

__device__ __forceinline__ unsigned short f2bf(float f) {
  union { float f; unsigned u; } v; v.f = f;
  unsigned r = v.u + 0x7FFFu + ((v.u >> 16) & 1u);
  return (unsigned short)(r >> 16);
}

typedef const __attribute__((address_space(1))) unsigned int* gas_t;
typedef __attribute__((address_space(3))) unsigned int* las_t;
__device__ __forceinline__ void gl2lds16(const void* g, void* l) {
  __builtin_amdgcn_global_load_lds((gas_t)g, (las_t)l, 16, 0, 0);
}

// ---------------------------------------------------------------------------
// fp32 -> bf16 conversion pass
// ---------------------------------------------------------------------------
__global__ __launch_bounds__(256) void conv_bf16(
    const float* __restrict__ q, const float* __restrict__ k, const float* __restrict__ v,
    const float* __restrict__ wq, const float* __restrict__ wk, const float* __restrict__ wv,
    const float* __restrict__ wo,
    us16* __restrict__ qb, us16* __restrict__ kb, us16* __restrict__ vb,
    us16* __restrict__ wqb, us16* __restrict__ wkb, us16* __restrict__ wvb,
    us16* __restrict__ wob)
{
  int b = blockIdx.x;
  int seg, off;
  if (b < 24576) { seg = b >> 13; off = b & 8191; }
  else { b -= 24576; seg = 3 + (b >> 10); off = b & 1023; }
  const float* s; us16* d;
  switch (seg) {
    case 0: s = q;  d = qb;  break;
    case 1: s = k;  d = kb;  break;
    case 2: s = v;  d = vb;  break;
    case 3: s = wq; d = wqb; break;
    case 4: s = wk; d = wkb; break;
    case 5: s = wv; d = wvb; break;
    default: s = wo; d = wob; break;
  }
  size_t idx = ((size_t)off * 256 + threadIdx.x) * 4;
  float4 f = *(const float4*)(s + idx);
  ushort4 u;
  u.x = f2bf(f.x); u.y = f2bf(f.y); u.z = f2bf(f.z); u.w = f2bf(f.w);
  *(ushort4*)(d + idx) = u;
}

// ---------------------------------------------------------------------------
// Projection GEMM (bf16): Y = X @ W^T + bias.
// z=0: plain [B,S,D] output (Q or K), scaled.  z=1: V -> [B,H,DH,S] transposed.
// ---------------------------------------------------------------------------
__global__ __launch_bounds__(256, 3) void gemm_qv(
    const us16* __restrict__ A0, const us16* __restrict__ A1,
    const us16* __restrict__ W0, const us16* __restrict__ W1,
    const float* __restrict__ bias0, const float* __restrict__ bias1,
    us16* __restrict__ out0, us16* __restrict__ out1, float scale)
{
  const int z = blockIdx.z;
  const us16* A  = z ? A1 : A0;
  const us16* Wt = z ? W1 : W0;
  const float* bias = z ? bias1 : bias0;

  __shared__ us16 As[128][64];
  __shared__ us16 Bs[128][64];
  const int tid = threadIdx.x;
  const int lane = tid & 63;
  const int w = tid >> 6;
  const int l15 = lane & 15, quad = lane >> 4;
  const int sw = l15 & 7;
  const int rowBase = blockIdx.x * 128, colBase = blockIdx.y * 128;
  const int srow = w * 32 + (lane >> 3);
  const int cu = (lane & 7) ^ ((lane >> 3) & 7);
  const us16* ga = A  + (size_t)(rowBase + srow) * ND + cu * 8;
  const us16* gb = Wt + (size_t)(colBase + srow) * ND + cu * 8;
  const int wr = (w >> 1) * 64, wc = (w & 1) * 64;

  f32x4 acc[4][4] = {};
  for (int kt = 0; kt < ND; kt += 64) {
    __syncthreads();
    #pragma unroll
    for (int c = 0; c < 4; ++c) {
      gl2lds16(ga + kt + c * 8 * ND, &As[w * 32 + c * 8][0]);
      gl2lds16(gb + kt + c * 8 * ND, &Bs[w * 32 + c * 8][0]);
    }
    __syncthreads();
    #pragma unroll
    for (int ks = 0; ks < 2; ++ks) {
      bf16x8 af[4], bfr[4];
      #pragma unroll
      for (int i = 0; i < 4; ++i)
        af[i]  = *(const bf16x8*)&As[wr + i * 16 + l15][((ks * 4 + quad) ^ sw) * 8];
      #pragma unroll
      for (int j = 0; j < 4; ++j)
        bfr[j] = *(const bf16x8*)&Bs[wc + j * 16 + l15][((ks * 4 + quad) ^ sw) * 8];
      #pragma unroll
      for (int i = 0; i < 4; ++i)
        #pragma unroll
        for (int j = 0; j < 4; ++j)
          acc[i][j] = __builtin_amdgcn_mfma_f32_16x16x32_bf16(af[i], bfr[j], acc[i][j], 0, 0, 0);
    }
  }

  if (z == 0) {
    #pragma unroll
    for (int i = 0; i < 4; ++i) {
      #pragma unroll
      for (int j = 0; j < 4; ++j) {
        int colg = colBase + wc + j * 16 + l15;
        float bval = bias[colg];
        #pragma unroll
        for (int r = 0; r < 4; ++r) {
          int rowg = rowBase + wr + i * 16 + quad * 4 + r;
          out0[(size_t)rowg * ND + colg] = f2bf((acc[i][j][r] + bval) * scale);
        }
      }
    }
  } else {
    #pragma unroll
    for (int i = 0; i < 4; ++i) {
      #pragma unroll
      for (int j = 0; j < 4; ++j) {
        int colg = colBase + wc + j * 16 + l15;
        float bval = bias[colg];
        int h_ = colg >> 6, d_ = colg & 63;
        int rowg0 = rowBase + wr + i * 16 + quad * 4;
        int b_ = rowg0 >> 11, s0 = rowg0 & (NS - 1);
        ushort4 vv;
        vv.x = f2bf(acc[i][j][0] + bval);
        vv.y = f2bf(acc[i][j][1] + bval);
        vv.z = f2bf(acc[i][j][2] + bval);
        vv.w = f2bf(acc[i][j][3] + bval);
        *(ushort4*)(out1 + ((size_t)(b_ * NH + h_) * NDH + d_) * NS + s0) = vv;
      }
    }
  }
}

// ---------------------------------------------------------------------------
// Flash attention, causal, fixed-max softmax (exp2 domain; scale folded in Q).
// 512 uniform blocks: each does q-tile pair (t, 15-t) = 34 key-tiles total.
// Single-barrier double-buffered K/V staging; per-wave 32x32 swizzled Ps;
// denominator via ones-MFMA (no shuffles). Q/K plain [B,S,D]; V [B,H,DH,S].
// ---------------------------------------------------------------------------
__global__ __launch_bounds__(256, 4) void attn(
    const us16* __restrict__ Qh, const us16* __restrict__ Kh,
    const us16* __restrict__ Vht, us16* __restrict__ ctx)
{
  __shared__ us16 Ks[2][64][64];
  __shared__ us16 Vts[2][64][64];
  __shared__ us16 Ps[4][32][32];    // XOR-swizzled 16B units
  us16* Qsta = &Vts[0][0][0];       // Q staging overlays Vts (16KB)

  const int bh = blockIdx.x >> 3;
  const int pr = blockIdx.x & 7;
  const int b_ = bh >> 4, h_ = bh & 15;
  const int tid = threadIdx.x, lane = tid & 63, w = tid >> 6;
  const int l15 = lane & 15, quad = lane >> 4;
  const int sw = l15 & 7;
  const int lr8 = lane >> 3;
  const int cu = (lane & 7) ^ (lr8 & 7);

  bf16x8 ones;
  #pragma unroll
  for (int i = 0; i < 8; ++i) ones[i] = (__bf16)1.0f;

  const us16* gkbase = Kh  + ((size_t)b_ * NS + w * 16 + lr8) * ND + h_ * NDH + cu * 8;
  const us16* gvbase = Vht + ((size_t)bh * NDH + w * 16 + lr8) * NS + cu * 8;

  for (int pass = 0; pass < 2; ++pass) {
    const int tq = pass ? (15 - pr) : pr;
    const int qb0 = tq * 128;
    const int nt = tq * 2 + 2;
    const int qw = qb0 + w * 32;

    __syncthreads();   // previous pass fully done with LDS
    {
      const us16* gq = Qh + ((size_t)b_ * NS + qb0 + w * 32 + lr8) * ND + h_ * NDH + cu * 8;
      #pragma unroll
      for (int u = 0; u < 4; ++u)
        gl2lds16(gq + (size_t)u * 8 * ND, Qsta + (w * 32 + u * 8) * 64);
    }
    __syncthreads();   // Q landed (compiler drains vmcnt before barrier)
    bf16x8 bq[2][2];
    #pragma unroll
    for (int ntl = 0; ntl < 2; ++ntl)
      #pragma unroll
      for (int c = 0; c < 2; ++c)
        bq[ntl][c] = *(const bf16x8*)(Qsta + (w * 32 + ntl * 16 + l15) * 64 +
                                      (((c * 4 + quad) ^ sw) * 8));
    __syncthreads();   // all waves done reading Q; Vts reusable

    // prefetch tile 0 -> buffer 0
    gl2lds16(gkbase,            &Ks[0][w * 16][0]);
    gl2lds16(gkbase + 8 * ND,   &Ks[0][w * 16 + 8][0]);
    gl2lds16(gvbase,            &Vts[0][w * 16][0]);
    gl2lds16(gvbase + 8 * NS,   &Vts[0][w * 16 + 8][0]);

    f32x4 o[2][4] = {};
    f32x4 o_l[2] = {};

    for (int it = 0; it < nt; ++it) {
      const int kb = it * 64;
      const int cur = it & 1;
      __syncthreads();   // tile `it` staged; prev compute done
      if (it + 1 < nt) {
        const int nxt = cur ^ 1;
        gl2lds16(gkbase + (size_t)(kb + 64) * ND,          &Ks[nxt][w * 16][0]);
        gl2lds16(gkbase + (size_t)(kb + 72) * ND,          &Ks[nxt][w * 16 + 8][0]);
        gl2lds16(gvbase + kb + 64,                         &Vts[nxt][w * 16][0]);
        gl2lds16(gvbase + kb + 64 + 8 * NS,                &Vts[nxt][w * 16 + 8][0]);
      }
      if (kb <= qw + 31) {
        const bool full = (kb + 63 <= qw);
        #pragma unroll
        for (int h2 = 0; h2 < 2; ++h2) {
          f32x4 s[2][2];
          #pragma unroll
          for (int mt = 0; mt < 2; ++mt) {
            bf16x8 ak0 = *(const bf16x8*)&Ks[cur][h2 * 32 + mt * 16 + l15][(quad ^ sw) * 8];
            bf16x8 ak1 = *(const bf16x8*)&Ks[cur][h2 * 32 + mt * 16 + l15][((4 + quad) ^ sw) * 8];
            #pragma unroll
            for (int ntl = 0; ntl < 2; ++ntl) {
              f32x4 t = {};
              t = __builtin_amdgcn_mfma_f32_16x16x32_bf16(ak0, bq[ntl][0], t, 0, 0, 0);
              t = __builtin_amdgcn_mfma_f32_16x16x32_bf16(ak1, bq[ntl][1], t, 0, 0, 0);
              s[mt][ntl] = t;
            }
          }
          #pragma unroll
          for (int mt = 0; mt < 2; ++mt)
            #pragma unroll
            for (int ntl = 0; ntl < 2; ++ntl) {
              u32 u[4];
              if (full) {
                #pragma unroll
                for (int r = 0; r < 4; ++r)
                  u[r] = __float_as_uint(__builtin_amdgcn_exp2f(s[mt][ntl][r]));
              } else {
                const int keyb = kb + h2 * 32 + mt * 16 + quad * 4;
                const int qg = qw + ntl * 16 + l15;
                #pragma unroll
                for (int r = 0; r < 4; ++r) {
                  float p = (keyb + r <= qg) ? __builtin_amdgcn_exp2f(s[mt][ntl][r]) : 0.f;
                  u[r] = __float_as_uint(p);
                }
              }
              u32 lo = (u[0] >> 16) | (u[1] & 0xffff0000u);
              u32 hi = (u[2] >> 16) | (u[3] & 0xffff0000u);
              int uswz = (mt * 2 + (quad >> 1)) ^ (l15 & 3);
              *(u32x2*)&Ps[w][ntl * 16 + l15][uswz * 8 + (quad & 1) * 4] = (u32x2){lo, hi};
            }
          #pragma unroll
          for (int ntl = 0; ntl < 2; ++ntl) {
            bf16x8 ap = *(const bf16x8*)&Ps[w][ntl * 16 + l15][(quad ^ (l15 & 3)) * 8];
            o_l[ntl] = __builtin_amdgcn_mfma_f32_16x16x32_bf16(ap, ones, o_l[ntl], 0, 0, 0);
            #pragma unroll
            for (int n = 0; n < 4; ++n) {
              bf16x8 bv = *(const bf16x8*)&Vts[cur][n * 16 + l15][((h2 * 4 + quad) ^ sw) * 8];
              o[ntl][n] = __builtin_amdgcn_mfma_f32_16x16x32_bf16(ap, bv, o[ntl][n], 0, 0, 0);
            }
          }
        }
      }
    }

    #pragma unroll
    for (int ntl = 0; ntl < 2; ++ntl) {
      #pragma unroll
      for (int r = 0; r < 4; ++r) {
        float inv = __builtin_amdgcn_rcpf(o_l[ntl][r]);
        int qg = qb0 + w * 32 + ntl * 16 + quad * 4 + r;
        us16* dst = ctx + ((size_t)b_ * NS + qg) * ND + h_ * NDH;
        #pragma unroll
        for (int n = 0; n < 4; ++n)
          dst[n * 16 + l15] = f2bf(o[ntl][n][r] * inv);
      }
    }
  }
}

// ---------------------------------------------------------------------------
// Output projection: out = ctx(bf16) @ wo^T(bf16) + bo, fp32 row-major
// ---------------------------------------------------------------------------
__global__ __launch_bounds__(256, 3) void gemm_out(
    const us16* __restrict__ A, const us16* __restrict__ Wt,
    const float* __restrict__ bias, float* __restrict__ out)
{
  __shared__ us16 As[128][64];
  __shared__ us16 Bs[128][64];
  const int tid = threadIdx.x;
  const int lane = tid & 63;
  const int w = tid >> 6;
  const int l15 = lane & 15, quad = lane >> 4;
  const int sw = l15 & 7;
  const int rowBase = blockIdx.x * 128, colBase = blockIdx.y * 128;
  const int srow = w * 32 + (lane >> 3);
  const int cu = (lane & 7) ^ ((lane >> 3) & 7);
  const us16* ga = A  + (size_t)(rowBase + srow) * ND + cu * 8;
  const us16* gb = Wt + (size_t)(colBase + srow) * ND + cu * 8;
  const int wr = (w >> 1) * 64, wc = (w & 1) * 64;

  f32x4 acc[4][4] = {};
  for (int kt = 0; kt < ND; kt += 64) {
    __syncthreads();
    #pragma unroll
    for (int c = 0; c < 4; ++c) {
      gl2lds16(ga + kt + c * 8 * ND, &As[w * 32 + c * 8][0]);
      gl2lds16(gb + kt + c * 8 * ND, &Bs[w * 32 + c * 8][0]);
    }
    __syncthreads();
    #pragma unroll
    for (int ks = 0; ks < 2; ++ks) {
      bf16x8 af[4], bfr[4];
      #pragma unroll
      for (int i = 0; i < 4; ++i)
        af[i]  = *(const bf16x8*)&As[wr + i * 16 + l15][((ks * 4 + quad) ^ sw) * 8];
      #pragma unroll
      for (int j = 0; j < 4; ++j)
        bfr[j] = *(const bf16x8*)&Bs[wc + j * 16 + l15][((ks * 4 + quad) ^ sw) * 8];
      #pragma unroll
      for (int i = 0; i < 4; ++i)
        #pragma unroll
        for (int j = 0; j < 4; ++j)
          acc[i][j] = __builtin_amdgcn_mfma_f32_16x16x32_bf16(af[i], bfr[j], acc[i][j], 0, 0, 0);
    }
  }

  #pragma unroll
  for (int i = 0; i < 4; ++i) {
    #pragma unroll
    for (int j = 0; j < 4; ++j) {
      int colg = colBase + wc + j * 16 + l15;
      float bval = bias[colg];
      #pragma unroll
      for (int r = 0; r < 4; ++r) {
        int rowg = rowBase + wr + i * 16 + quad * 4 + r;
        out[(size_t)rowg * ND + colg] = acc[i][j][r] + bval;
      }
    }
  }
}

extern "C" void kernel_launch(void* const* d_in, const int* in_sizes, int n_in,
                              void* d_out, int out_size, void* d_ws, size_t ws_size,
                              hipStream_t stream) {
  const float* q  = (const float*)d_in[0];
  const float* k  = (const float*)d_in[1];
  const float* v  = (const float*)d_in[2];
  // d_in[3] = mask (causal by construction)
  const float* wq = (const float*)d_in[4];
  const float* bq_ = (const float*)d_in[5];
  const float* wk = (const float*)d_in[6];
  const float* bk_ = (const float*)d_in[7];
  const float* wv = (const float*)d_in[8];
  const float* bv_ = (const float*)d_in[9];
  const float* wo = (const float*)d_in[10];
  const float* bo_ = (const float*)d_in[11];

  us16* ws = (us16*)d_ws;
  us16* qb  = ws;                      // later reused as Kh
  us16* kb  = ws + (size_t)E_;
  us16* vb  = ws + (size_t)2 * E_;     // later reused as ctx
  us16* wqb = ws + (size_t)3 * E_;
  us16* wkb = wqb + W_;
  us16* wvb = wkb + W_;
  us16* wob = wvb + W_;
  us16* Kh  = qb;                      // written after QV launch consumed qb
  us16* ctx = vb;                      // written after QV launch consumed vb
  us16* Vht = (us16*)d_out;            // d_out scratch: dead before gemm_out
  us16* Qh  = (us16*)d_out + (size_t)E_;

  const float qscale = 0.125f * 1.44269504088896340736f;  // 1/sqrt(DH)*log2(e)

  conv_bf16<<<28672, 256, 0, stream>>>(q, k, v, wq, wk, wv, wo,
                                       qb, kb, vb, wqb, wkb, wvb, wob);
  gemm_qv<<<dim3(64, 8, 2), 256, 0, stream>>>(qb, vb, wqb, wvb, bq_, bv_,
                                              Qh, Vht, qscale);
  gemm_qv<<<dim3(64, 8, 1), 256, 0, stream>>>(kb, kb, wkb, wkb, bk_, bk_,
                                              Kh, Kh, 1.0f);
  attn<<<512, 256, 0, stream>>>(Qh, Kh, Vht, ctx);
  gemm_out<<<dim3(64, 8), 256, 0, stream>>>(ctx, wob, bo_, (float*)d_out);
}

// Round 5
// 316.716 us; speedup vs baseline: 1.8497x; 1.0100x over previous
//
#include <hip/hip_runtime.h>
#include <hip/hip_bf16.h>

#define NB 4
#define NS 2048
#define ND 1024
#define NH 16
#define NDH 64
#define E_ 8388608   // NB*NS*ND
#define W_ 1048576   // ND*ND

typedef __attribute__((ext_vector_type(8))) __bf16 bf16x8;
typedef __attribute__((ext_vector_type(4))) float f32x4;
typedef __attribute__((ext_vector_type(2))) unsigned int u32x2;
typedef unsigned short us16;
typedef unsigned int u32;

__device__ __forceinline__ unsigned short f2bf(float f) {
  union { float f; unsigned u; } v; v.f = f;
  unsigned r = v.u + 0x7FFFu + ((v.u >> 16) & 1u);
  return (unsigned short)(r >> 16);
}

typedef const __attribute__((address_space(1))) unsigned int* gas_t;
typedef __attribute__((address_space(3))) unsigned int* las_t;
__device__ __forceinline__ void gl2lds16(const void* g, void* l) {
  __builtin_amdgcn_global_load_lds((gas_t)g, (las_t)l, 16, 0, 0);
}

// ---------------------------------------------------------------------------
// fp32 -> bf16 conversion pass
// ---------------------------------------------------------------------------
__global__ __launch_bounds__(256) void conv_bf16(
    const float* __restrict__ q, const float* __restrict__ k, const float* __restrict__ v,
    const float* __restrict__ wq, const float* __restrict__ wk, const float* __restrict__ wv,
    const float* __restrict__ wo,
    us16* __restrict__ qb, us16* __restrict__ kb, us16* __restrict__ vb,
    us16* __restrict__ wqb, us16* __restrict__ wkb, us16* __restrict__ wvb,
    us16* __restrict__ wob)
{
  int b = blockIdx.x;
  int seg, off;
  if (b < 24576) { seg = b >> 13; off = b & 8191; }
  else { b -= 24576; seg = 3 + (b >> 10); off = b & 1023; }
  const float* s; us16* d;
  switch (seg) {
    case 0: s = q;  d = qb;  break;
    case 1: s = k;  d = kb;  break;
    case 2: s = v;  d = vb;  break;
    case 3: s = wq; d = wqb; break;
    case 4: s = wk; d = wkb; break;
    case 5: s = wv; d = wvb; break;
    default: s = wo; d = wob; break;
  }
  size_t idx = ((size_t)off * 256 + threadIdx.x) * 4;
  float4 f = *(const float4*)(s + idx);
  ushort4 u;
  u.x = f2bf(f.x); u.y = f2bf(f.y); u.z = f2bf(f.z); u.w = f2bf(f.w);
  *(ushort4*)(d + idx) = u;
}

// ---------------------------------------------------------------------------
// Projection GEMM (bf16): Y = X @ W^T + bias. blockIdx.z -> seg via (s0,s1,s2).
// seg 0: Q plain [B,S,D] scaled; seg 1: K plain [B,S,D]; seg 2: V -> [B,H,DH,S].
// ---------------------------------------------------------------------------
__global__ __launch_bounds__(256, 3) void gemm_proj3(
    const us16* __restrict__ A0, const us16* __restrict__ A1, const us16* __restrict__ A2,
    const us16* __restrict__ W0, const us16* __restrict__ W1, const us16* __restrict__ W2,
    const float* __restrict__ b0, const float* __restrict__ b1, const float* __restrict__ b2,
    us16* __restrict__ o0, us16* __restrict__ o1, us16* __restrict__ o2,
    float qscale, int s0, int s1, int s2)
{
  const int seg = (blockIdx.z == 0) ? s0 : (blockIdx.z == 1) ? s1 : s2;
  const us16* A  = (blockIdx.z == 0) ? A0 : (blockIdx.z == 1) ? A1 : A2;
  const us16* Wt = (blockIdx.z == 0) ? W0 : (blockIdx.z == 1) ? W1 : W2;
  const float* bias = (blockIdx.z == 0) ? b0 : (blockIdx.z == 1) ? b1 : b2;
  us16* out = (blockIdx.z == 0) ? o0 : (blockIdx.z == 1) ? o1 : o2;
  const float scale = (seg == 0) ? qscale : 1.0f;

  __shared__ us16 As[128][64];
  __shared__ us16 Bs[128][64];
  const int tid = threadIdx.x;
  const int lane = tid & 63;
  const int w = tid >> 6;
  const int l15 = lane & 15, quad = lane >> 4;
  const int sw = l15 & 7;
  const int rowBase = blockIdx.x * 128, colBase = blockIdx.y * 128;
  const int srow = w * 32 + (lane >> 3);
  const int cu = (lane & 7) ^ ((lane >> 3) & 7);
  const us16* ga = A  + (size_t)(rowBase + srow) * ND + cu * 8;
  const us16* gb = Wt + (size_t)(colBase + srow) * ND + cu * 8;
  const int wr = (w >> 1) * 64, wc = (w & 1) * 64;

  f32x4 acc[4][4] = {};
  for (int kt = 0; kt < ND; kt += 64) {
    __syncthreads();
    #pragma unroll
    for (int c = 0; c < 4; ++c) {
      gl2lds16(ga + kt + c * 8 * ND, &As[w * 32 + c * 8][0]);
      gl2lds16(gb + kt + c * 8 * ND, &Bs[w * 32 + c * 8][0]);
    }
    __syncthreads();
    #pragma unroll
    for (int ks = 0; ks < 2; ++ks) {
      bf16x8 af[4], bfr[4];
      #pragma unroll
      for (int i = 0; i < 4; ++i)
        af[i]  = *(const bf16x8*)&As[wr + i * 16 + l15][((ks * 4 + quad) ^ sw) * 8];
      #pragma unroll
      for (int j = 0; j < 4; ++j)
        bfr[j] = *(const bf16x8*)&Bs[wc + j * 16 + l15][((ks * 4 + quad) ^ sw) * 8];
      #pragma unroll
      for (int i = 0; i < 4; ++i)
        #pragma unroll
        for (int j = 0; j < 4; ++j)
          acc[i][j] = __builtin_amdgcn_mfma_f32_16x16x32_bf16(af[i], bfr[j], acc[i][j], 0, 0, 0);
    }
  }

  if (seg < 2) {
    #pragma unroll
    for (int i = 0; i < 4; ++i) {
      #pragma unroll
      for (int j = 0; j < 4; ++j) {
        int colg = colBase + wc + j * 16 + l15;
        float bval = bias[colg];
        #pragma unroll
        for (int r = 0; r < 4; ++r) {
          int rowg = rowBase + wr + i * 16 + quad * 4 + r;
          out[(size_t)rowg * ND + colg] = f2bf((acc[i][j][r] + bval) * scale);
        }
      }
    }
  } else {
    #pragma unroll
    for (int i = 0; i < 4; ++i) {
      #pragma unroll
      for (int j = 0; j < 4; ++j) {
        int colg = colBase + wc + j * 16 + l15;
        float bval = bias[colg];
        int h_ = colg >> 6, d_ = colg & 63;
        int rowg0 = rowBase + wr + i * 16 + quad * 4;
        int b_ = rowg0 >> 11, sr0 = rowg0 & (NS - 1);
        ushort4 vv;
        vv.x = f2bf(acc[i][j][0] + bval);
        vv.y = f2bf(acc[i][j][1] + bval);
        vv.z = f2bf(acc[i][j][2] + bval);
        vv.w = f2bf(acc[i][j][3] + bval);
        *(ushort4*)(out + ((size_t)(b_ * NH + h_) * NDH + d_) * NS + sr0) = vv;
      }
    }
  }
}

// ---------------------------------------------------------------------------
// Flash attention, causal, fixed-max softmax (exp2 domain; scale folded in Q).
// 512 blocks; bh = blockIdx.x & 63 so one head's 8 pair-blocks share an XCD
// (L2 locality). Each block: q-tile pair (t, 15-t) = 34 key-tiles. Single-
// barrier double-buffered K/V; per-wave swizzled Ps; denominator = ones-MFMA.
// ---------------------------------------------------------------------------
__global__ __launch_bounds__(256, 4) void attn(
    const us16* __restrict__ Qh, const us16* __restrict__ Kh,
    const us16* __restrict__ Vht, us16* __restrict__ ctx)
{
  __shared__ us16 Ks[2][64][64];
  __shared__ us16 Vts[2][64][64];
  __shared__ us16 Ps[4][32][32];    // XOR-swizzled 16B units
  us16* Qsta = &Vts[0][0][0];       // Q staging overlays Vts (16KB)

  const int bh = blockIdx.x & 63;   // %8 XCD round-robin: same head -> same XCD
  const int pr = blockIdx.x >> 6;
  const int b_ = bh >> 4, h_ = bh & 15;
  const int tid = threadIdx.x, lane = tid & 63, w = tid >> 6;
  const int l15 = lane & 15, quad = lane >> 4;
  const int sw = l15 & 7;
  const int lr8 = lane >> 3;
  const int cu = (lane & 7) ^ (lr8 & 7);

  bf16x8 ones;
  #pragma unroll
  for (int i = 0; i < 8; ++i) ones[i] = (__bf16)1.0f;

  const us16* gkbase = Kh  + ((size_t)b_ * NS + w * 16 + lr8) * ND + h_ * NDH + cu * 8;
  const us16* gvbase = Vht + ((size_t)bh * NDH + w * 16 + lr8) * NS + cu * 8;

  for (int pass = 0; pass < 2; ++pass) {
    const int tq = pass ? (15 - pr) : pr;
    const int qb0 = tq * 128;
    const int nt = tq * 2 + 2;
    const int qw = qb0 + w * 32;

    __syncthreads();   // previous pass fully done with LDS
    {
      const us16* gq = Qh + ((size_t)b_ * NS + qb0 + w * 32 + lr8) * ND + h_ * NDH + cu * 8;
      #pragma unroll
      for (int u = 0; u < 4; ++u)
        gl2lds16(gq + (size_t)u * 8 * ND, Qsta + (w * 32 + u * 8) * 64);
    }
    __syncthreads();   // Q landed
    bf16x8 bq[2][2];
    #pragma unroll
    for (int ntl = 0; ntl < 2; ++ntl)
      #pragma unroll
      for (int c = 0; c < 2; ++c)
        bq[ntl][c] = *(const bf16x8*)(Qsta + (w * 32 + ntl * 16 + l15) * 64 +
                                      (((c * 4 + quad) ^ sw) * 8));
    __syncthreads();   // all waves done reading Q; Vts reusable

    // prefetch tile 0 -> buffer 0
    gl2lds16(gkbase,            &Ks[0][w * 16][0]);
    gl2lds16(gkbase + 8 * ND,   &Ks[0][w * 16 + 8][0]);
    gl2lds16(gvbase,            &Vts[0][w * 16][0]);
    gl2lds16(gvbase + 8 * NS,   &Vts[0][w * 16 + 8][0]);

    f32x4 o[2][4] = {};
    f32x4 o_l[2] = {};

    for (int it = 0; it < nt; ++it) {
      const int kb = it * 64;
      const int cur = it & 1;
      __syncthreads();   // tile `it` staged; prev compute done
      if (it + 1 < nt) {
        const int nxt = cur ^ 1;
        gl2lds16(gkbase + (size_t)(kb + 64) * ND,          &Ks[nxt][w * 16][0]);
        gl2lds16(gkbase + (size_t)(kb + 72) * ND,          &Ks[nxt][w * 16 + 8][0]);
        gl2lds16(gvbase + kb + 64,                         &Vts[nxt][w * 16][0]);
        gl2lds16(gvbase + kb + 64 + 8 * NS,                &Vts[nxt][w * 16 + 8][0]);
      }
      if (kb <= qw + 31) {
        const bool full = (kb + 63 <= qw);
        #pragma unroll
        for (int h2 = 0; h2 < 2; ++h2) {
          f32x4 s[2][2];
          #pragma unroll
          for (int mt = 0; mt < 2; ++mt) {
            bf16x8 ak0 = *(const bf16x8*)&Ks[cur][h2 * 32 + mt * 16 + l15][(quad ^ sw) * 8];
            bf16x8 ak1 = *(const bf16x8*)&Ks[cur][h2 * 32 + mt * 16 + l15][((4 + quad) ^ sw) * 8];
            #pragma unroll
            for (int ntl = 0; ntl < 2; ++ntl) {
              f32x4 t = {};
              t = __builtin_amdgcn_mfma_f32_16x16x32_bf16(ak0, bq[ntl][0], t, 0, 0, 0);
              t = __builtin_amdgcn_mfma_f32_16x16x32_bf16(ak1, bq[ntl][1], t, 0, 0, 0);
              s[mt][ntl] = t;
            }
          }
          #pragma unroll
          for (int mt = 0; mt < 2; ++mt)
            #pragma unroll
            for (int ntl = 0; ntl < 2; ++ntl) {
              u32 u[4];
              if (full) {
                #pragma unroll
                for (int r = 0; r < 4; ++r)
                  u[r] = __float_as_uint(__builtin_amdgcn_exp2f(s[mt][ntl][r]));
              } else {
                const int keyb = kb + h2 * 32 + mt * 16 + quad * 4;
                const int qg = qw + ntl * 16 + l15;
                #pragma unroll
                for (int r = 0; r < 4; ++r) {
                  float p = (keyb + r <= qg) ? __builtin_amdgcn_exp2f(s[mt][ntl][r]) : 0.f;
                  u[r] = __float_as_uint(p);
                }
              }
              u32 lo = (u[0] >> 16) | (u[1] & 0xffff0000u);
              u32 hi = (u[2] >> 16) | (u[3] & 0xffff0000u);
              int uswz = (mt * 2 + (quad >> 1)) ^ (l15 & 3);
              *(u32x2*)&Ps[w][ntl * 16 + l15][uswz * 8 + (quad & 1) * 4] = (u32x2){lo, hi};
            }
          bf16x8 bv[4];
          #pragma unroll
          for (int n = 0; n < 4; ++n)
            bv[n] = *(const bf16x8*)&Vts[cur][n * 16 + l15][((h2 * 4 + quad) ^ sw) * 8];
          #pragma unroll
          for (int ntl = 0; ntl < 2; ++ntl) {
            bf16x8 ap = *(const bf16x8*)&Ps[w][ntl * 16 + l15][(quad ^ (l15 & 3)) * 8];
            o_l[ntl] = __builtin_amdgcn_mfma_f32_16x16x32_bf16(ap, ones, o_l[ntl], 0, 0, 0);
            #pragma unroll
            for (int n = 0; n < 4; ++n)
              o[ntl][n] = __builtin_amdgcn_mfma_f32_16x16x32_bf16(ap, bv[n], o[ntl][n], 0, 0, 0);
          }
        }
      }
    }

    #pragma unroll
    for (int ntl = 0; ntl < 2; ++ntl) {
      #pragma unroll
      for (int r = 0; r < 4; ++r) {
        float inv = __builtin_amdgcn_rcpf(o_l[ntl][r]);
        int qg = qb0 + w * 32 + ntl * 16 + quad * 4 + r;
        us16* dst = ctx + ((size_t)b_ * NS + qg) * ND + h_ * NDH;
        #pragma unroll
        for (int n = 0; n < 4; ++n)
          dst[n * 16 + l15] = f2bf(o[ntl][n][r] * inv);
      }
    }
  }
}

// ---------------------------------------------------------------------------
// Output projection: out = ctx(bf16) @ wo^T(bf16) + bo, fp32 row-major
// ---------------------------------------------------------------------------
__global__ __launch_bounds__(256, 3) void gemm_out(
    const us16* __restrict__ A, const us16* __restrict__ Wt,
    const float* __restrict__ bias, float* __restrict__ out)
{
  __shared__ us16 As[128][64];
  __shared__ us16 Bs[128][64];
  const int tid = threadIdx.x;
  const int lane = tid & 63;
  const int w = tid >> 6;
  const int l15 = lane & 15, quad = lane >> 4;
  const int sw = l15 & 7;
  const int rowBase = blockIdx.x * 128, colBase = blockIdx.y * 128;
  const int srow = w * 32 + (lane >> 3);
  const int cu = (lane & 7) ^ ((lane >> 3) & 7);
  const us16* ga = A  + (size_t)(rowBase + srow) * ND + cu * 8;
  const us16* gb = Wt + (size_t)(colBase + srow) * ND + cu * 8;
  const int wr = (w >> 1) * 64, wc = (w & 1) * 64;

  f32x4 acc[4][4] = {};
  for (int kt = 0; kt < ND; kt += 64) {
    __syncthreads();
    #pragma unroll
    for (int c = 0; c < 4; ++c) {
      gl2lds16(ga + kt + c * 8 * ND, &As[w * 32 + c * 8][0]);
      gl2lds16(gb + kt + c * 8 * ND, &Bs[w * 32 + c * 8][0]);
    }
    __syncthreads();
    #pragma unroll
    for (int ks = 0; ks < 2; ++ks) {
      bf16x8 af[4], bfr[4];
      #pragma unroll
      for (int i = 0; i < 4; ++i)
        af[i]  = *(const bf16x8*)&As[wr + i * 16 + l15][((ks * 4 + quad) ^ sw) * 8];
      #pragma unroll
      for (int j = 0; j < 4; ++j)
        bfr[j] = *(const bf16x8*)&Bs[wc + j * 16 + l15][((ks * 4 + quad) ^ sw) * 8];
      #pragma unroll
      for (int i = 0; i < 4; ++i)
        #pragma unroll
        for (int j = 0; j < 4; ++j)
          acc[i][j] = __builtin_amdgcn_mfma_f32_16x16x32_bf16(af[i], bfr[j], acc[i][j], 0, 0, 0);
    }
  }

  #pragma unroll
  for (int i = 0; i < 4; ++i) {
    #pragma unroll
    for (int j = 0; j < 4; ++j) {
      int colg = colBase + wc + j * 16 + l15;
      float bval = bias[colg];
      #pragma unroll
      for (int r = 0; r < 4; ++r) {
        int rowg = rowBase + wr + i * 16 + quad * 4 + r;
        out[(size_t)rowg * ND + colg] = acc[i][j][r] + bval;
      }
    }
  }
}

extern "C" void kernel_launch(void* const* d_in, const int* in_sizes, int n_in,
                              void* d_out, int out_size, void* d_ws, size_t ws_size,
                              hipStream_t stream) {
  const float* q  = (const float*)d_in[0];
  const float* k  = (const float*)d_in[1];
  const float* v  = (const float*)d_in[2];
  // d_in[3] = mask (causal by construction)
  const float* wq = (const float*)d_in[4];
  const float* bq_ = (const float*)d_in[5];
  const float* wk = (const float*)d_in[6];
  const float* bk_ = (const float*)d_in[7];
  const float* wv = (const float*)d_in[8];
  const float* bv_ = (const float*)d_in[9];
  const float* wo = (const float*)d_in[10];
  const float* bo_ = (const float*)d_in[11];

  us16* ws = (us16*)d_ws;
  us16* qb  = ws;
  us16* kb  = ws + (size_t)E_;
  us16* vb  = ws + (size_t)2 * E_;     // later reused as ctx
  us16* wqb = ws + (size_t)3 * E_;
  us16* wkb = wqb + W_;
  us16* wvb = wkb + W_;
  us16* wob = wvb + W_;
  us16* KhF = wob + W_;                // fused-path K output (fresh region)
  us16* ctx = vb;
  us16* Vht = (us16*)d_out;            // d_out scratch: dead before gemm_out
  us16* Qh  = (us16*)d_out + (size_t)E_;

  const float qscale = 0.125f * 1.44269504088896340736f;  // 1/sqrt(DH)*log2(e)
  const bool fused = ws_size >= ((size_t)4 * E_ + 4 * W_) * 2;

  conv_bf16<<<28672, 256, 0, stream>>>(q, k, v, wq, wk, wv, wo,
                                       qb, kb, vb, wqb, wkb, wvb, wob);
  if (fused) {
    gemm_proj3<<<dim3(64, 8, 3), 256, 0, stream>>>(
        qb, kb, vb, wqb, wkb, wvb, bq_, bk_, bv_, Qh, KhF, Vht, qscale, 0, 1, 2);
    attn<<<512, 256, 0, stream>>>(Qh, KhF, Vht, ctx);
  } else {
    gemm_proj3<<<dim3(64, 8, 2), 256, 0, stream>>>(
        qb, vb, vb, wqb, wvb, wvb, bq_, bv_, bv_, Qh, Vht, Vht, qscale, 0, 2, 2);
    gemm_proj3<<<dim3(64, 8, 1), 256, 0, stream>>>(
        kb, kb, kb, wkb, wkb, wkb, bk_, bk_, bk_, qb, qb, qb, qscale, 1, 1, 1);
    attn<<<512, 256, 0, stream>>>(Qh, qb, Vht, ctx);
  }
  gemm_out<<<dim3(64, 8), 256, 0, stream>>>(ctx, wob, bo_, (float*)d_out);
}